// Round 8
// baseline (354.870 us; speedup 1.0000x reference)
//
#include <hip/hip_runtime.h>
#include <hip/hip_bf16.h>

// B=2, T=2048, C=1024, H=16, D=64
#define Bn 2
#define Tn 2048
#define Cn 1024
#define Hn 16
#define Dn 64
#define Mdim 4096   // B*T
#define Ndim 3072   // 3*C
#define Kdim 1024   // C

typedef unsigned short u16;
typedef __attribute__((ext_vector_type(8))) short bf16x8;   // 8 bf16 (4 VGPRs)
typedef __attribute__((ext_vector_type(4))) float f32x4;

__device__ __forceinline__ u16 f2bf(float v) {
    unsigned int x = __builtin_bit_cast(unsigned int, v);
    unsigned int r = (x + 0x7fffu + ((x >> 16) & 1u)) >> 16;  // RNE
    return (u16)r;
}

__device__ __forceinline__ unsigned int pack2(float a, float b) {
    return (unsigned int)f2bf(a) | ((unsigned int)f2bf(b) << 16);
}

// async global->LDS, 16B per lane. LDS dest = uniform base + lane*16 (m97).
__device__ __forceinline__ void async16(const void* g, void* l) {
    __builtin_amdgcn_global_load_lds(
        (const __attribute__((address_space(1))) void*)g,
        (__attribute__((address_space(3))) void*)(unsigned int)(unsigned long long)l,
        16, 0, 0);
}

// Inline dtype probe over X[0..511]: bf16 stream -> ~512 hits, fp32 -> ~66.
__device__ __forceinline__ int probe_inline(const unsigned int* __restrict__ X, int tid) {
    const int lane = tid & 63;
    int cnt = 0;
    #pragma unroll
    for (int i = 0; i < 8; i++) {
        unsigned int e = (X[lane * 8 + i] >> 7) & 0xFFu;
        cnt += (e >= 100u && e < 134u) ? 1 : 0;
    }
    #pragma unroll
    for (int off = 1; off < 64; off <<= 1) cnt += __shfl_xor(cnt, off);
    return cnt > 256 ? 1 : 0;
}

// ---------------------------------------------------------------------------
// Convert: X,W -> contiguous bf16 in ws (fp32: RNE; bf16: copy). Inline probe;
// block 0 persists the flag for attn.
// ---------------------------------------------------------------------------
#define NXC ((size_t)Mdim * Kdim / 8)   // 524288 chunks of 8 elems
#define NWC ((size_t)Ndim * Kdim / 8)   // 393216

__global__ __launch_bounds__(256) void convert_in(
        const void* __restrict__ Xv, const void* __restrict__ Wv,
        u16* __restrict__ Xb, u16* __restrict__ Wb, int* __restrict__ flag) {
    const int isbf = probe_inline((const unsigned int*)Xv, threadIdx.x);
    if (blockIdx.x == 0 && threadIdx.x == 0) *flag = isbf;
    size_t i = (size_t)blockIdx.x * 256 + threadIdx.x;
    if (i >= NXC + NWC) return;
    const void* src; u16* dst; size_t off;
    if (i < NXC) { src = Xv; dst = Xb; off = i; }
    else         { src = Wv; dst = Wb; off = i - NXC; }
    if (isbf) {
        ((uint4*)dst)[off] = ((const uint4*)src)[off];
    } else {
        const float4* s = (const float4*)src + off * 2;
        float4 a = s[0], b = s[1];
        ((uint4*)dst)[off] = (uint4){pack2(a.x, a.y), pack2(a.z, a.w),
                                     pack2(b.x, b.y), pack2(b.z, b.w)};
    }
}

// ---------------------------------------------------------------------------
// Kernel 1: QKV GEMM (m97: global_load_lds w16, unpadded LDS) — R6 version.
// qkv[m][f] = sum_c Xb[m][c]*Wb[f][c]. Scatters Q (x1/8), K, Vt.
// ---------------------------------------------------------------------------
__global__ __launch_bounds__(256) void qkv_gemm(
        const u16* __restrict__ Xb, const u16* __restrict__ Wb,
        u16* __restrict__ Q, u16* __restrict__ Kc, u16* __restrict__ Vt) {
    __shared__ __align__(16) u16 sA[128 * 32];
    __shared__ __align__(16) u16 sB[128 * 32];

    const int tid  = threadIdx.x;
    const int lane = tid & 63;
    const int wv   = tid >> 6;
    const int quad = lane >> 4;
    const int r16  = lane & 15;
    const int m0 = blockIdx.y * 128;
    const int n0 = blockIdx.x * 128;
    const int wm = (wv >> 1) * 64;
    const int wn = (wv & 1) * 64;
    const int l4 = lane >> 2;
    const int c8 = (lane & 3) * 8;

    f32x4 acc[4][4];
    #pragma unroll
    for (int i = 0; i < 4; i++)
        #pragma unroll
        for (int j = 0; j < 4; j++)
            acc[i][j] = (f32x4){0.f, 0.f, 0.f, 0.f};

    for (int k0 = 0; k0 < Kdim; k0 += 32) {
        __syncthreads();
        #pragma unroll
        for (int i = 0; i < 2; i++) {
            const int rg = (wv + 4 * i) * 16;
            async16(Xb + (size_t)(m0 + rg + l4) * Kdim + k0 + c8, sA + rg * 32);
            async16(Wb + (size_t)(n0 + rg + l4) * Kdim + k0 + c8, sB + rg * 32);
        }
        __syncthreads();

        bf16x8 af[4], bfr[4];
        #pragma unroll
        for (int mt = 0; mt < 4; mt++)
            af[mt] = *(const bf16x8*)(sA + (wm + mt * 16 + r16) * 32 + quad * 8);
        #pragma unroll
        for (int nt = 0; nt < 4; nt++)
            bfr[nt] = *(const bf16x8*)(sB + (wn + nt * 16 + r16) * 32 + quad * 8);
        #pragma unroll
        for (int mt = 0; mt < 4; mt++)
            #pragma unroll
            for (int nt = 0; nt < 4; nt++)
                acc[mt][nt] = __builtin_amdgcn_mfma_f32_16x16x32_bf16(
                    af[mt], bfr[nt], acc[mt][nt], 0, 0, 0);
    }

    // Epilogue: C/D layout col=lane&15 (=n), row=quad*4+reg (=m) [m89/m91]
    #pragma unroll
    for (int mt = 0; mt < 4; mt++) {
        #pragma unroll
        for (int nt = 0; nt < 4; nt++) {
            #pragma unroll
            for (int r = 0; r < 4; r++) {
                int m = m0 + wm + mt * 16 + quad * 4 + r;
                int f = n0 + wn + nt * 16 + r16;
                float v = acc[mt][nt][r];
                int b = m >> 11, t = m & 2047;
                int sect = f >> 10;
                int h = (f >> 6) & 15;
                int d = f & 63;
                int bh = b * Hn + h;
                if (sect == 0) {
                    Q[((size_t)(bh * Tn + t)) * Dn + d] = f2bf(v * 0.125f);
                } else if (sect == 1) {
                    Kc[((size_t)(bh * Tn + t)) * Dn + d] = f2bf(v);
                } else {
                    Vt[((size_t)(bh * Dn + d)) * Tn + t] = f2bf(v);
                }
            }
        }
    }
}

// ---------------------------------------------------------------------------
// Kernel 2: causal flash attention, transposed (S^T = K·Q^T, C-init = -8 bakes
// the softmax shift into the MFMA). P^T -> PV B-operand via in-register lane
// shuffles (R6 path). Split-K: 8 waves, kb ≡ w (mod 8); combine via LDS
// ds_add_f32 (per-lane addresses, conflict-free). Fixed-shift softmax.
// ---------------------------------------------------------------------------
__global__ __launch_bounds__(512) void attn(
        const u16* __restrict__ Q, const u16* __restrict__ Kc,
        const u16* __restrict__ Vt, void* __restrict__ Y,
        const int* __restrict__ flag) {
    __shared__ float sO[2][4][4][64];   // 8192 B
    __shared__ float sL[2][64];         // 512 B

    const int isbf = *flag;
    const int tid  = threadIdx.x;
    const int lane = tid & 63;
    const int w    = tid >> 6;      // split-K index 0..7
    const int quad = lane >> 4;
    const int r16  = lane & 15;
    const int bh = blockIdx.x;                   // 0..31
    const int qt = gridDim.y - 1 - blockIdx.y;   // deep tiles first
    const int q0 = qt * 32;
    const size_t qkBase = (size_t)bh * Tn * Dn;
    const size_t vBase  = (size_t)bh * Dn * Tn;

    // Q frags (B-operand of S^T): B[k=quad*8+j][n=r16]
    bf16x8 aq[2][2];
    #pragma unroll
    for (int mt = 0; mt < 2; mt++) {
        const u16* qp = Q + qkBase + (size_t)(q0 + mt * 16 + r16) * Dn;
        aq[mt][0] = *(const bf16x8*)(qp + quad * 8);
        aq[mt][1] = *(const bf16x8*)(qp + 32 + quad * 8);
    }

    float lacc[2] = {0.f, 0.f};
    f32x4 o[2][4];   // O^T tiles [mt][dt], C-layout: row=d_local=quad*4+r, col=q=r16
    #pragma unroll
    for (int mt = 0; mt < 2; mt++)
        #pragma unroll
        for (int dt = 0; dt < 4; dt++) o[mt][dt] = (f32x4){0.f, 0.f, 0.f, 0.f};

    const int nkb = (q0 >> 6) + 1;
    for (int kb = w; kb < nkb; kb += 8) {
        const int kbase = kb * 64;
        const int diag = (kb == nkb - 1);

        // K frags (A-operand of S^T): A[m=key16=r16][k=quad*8+j]
        bf16x8 kf[4][2];
        #pragma unroll
        for (int nt = 0; nt < 4; nt++) {
            const u16* kp = Kc + qkBase + (size_t)(kbase + nt * 16 + r16) * Dn;
            kf[nt][0] = *(const bf16x8*)(kp + quad * 8);
            kf[nt][1] = *(const bf16x8*)(kp + 32 + quad * 8);
        }
        // V frags (A-operand of PV): A[m=d16=r16][k=quad*8+j]
        bf16x8 vf[4][2];
        #pragma unroll
        for (int dt = 0; dt < 4; dt++) {
            const u16* vp = Vt + vBase + (size_t)(dt * 16 + r16) * Tn + kbase;
            vf[dt][0] = *(const bf16x8*)(vp + quad * 8);
            vf[dt][1] = *(const bf16x8*)(vp + 32 + quad * 8);
        }

        #pragma unroll
        for (int mt = 0; mt < 2; mt++) {
            // S^T tile nt: value(lane(quad,r16), reg r) = S^T[nt*16+quad*4+r][r16]
            // C-init -8 bakes the softmax shift into the MFMA.
            f32x4 s[4];
            #pragma unroll
            for (int nt = 0; nt < 4; nt++) {
                f32x4 z = (f32x4){-8.f, -8.f, -8.f, -8.f};
                z = __builtin_amdgcn_mfma_f32_16x16x32_bf16(kf[nt][0], aq[mt][0], z, 0, 0, 0);
                z = __builtin_amdgcn_mfma_f32_16x16x32_bf16(kf[nt][1], aq[mt][1], z, 0, 0, 0);
                s[nt] = z;
            }
            if (diag) {
                const int query = q0 + mt * 16 + r16;
                #pragma unroll
                for (int nt = 0; nt < 4; nt++)
                    #pragma unroll
                    for (int r = 0; r < 4; r++) {
                        int key = kbase + nt * 16 + quad * 4 + r;
                        if (key > query) s[nt][r] = -1e30f;
                    }
            }
            // p = exp(s); accumulate l; pack pairs for the lane-shuffle transpose
            unsigned int pk[4][2];
            #pragma unroll
            for (int nt = 0; nt < 4; nt++) {
                float p0 = __expf(s[nt][0]);
                float p1 = __expf(s[nt][1]);
                float p2 = __expf(s[nt][2]);
                float p3 = __expf(s[nt][3]);
                lacc[mt] += (p0 + p1) + (p2 + p3);
                pk[nt][0] = pack2(p0, p1);
                pk[nt][1] = pack2(p2, p3);
            }
            // build PV B-frags in-register: B[k=quad*8+j][n=r16]
            #pragma unroll
            for (int kc = 0; kc < 2; kc++) {
                int4 bq;
                #pragma unroll
                for (int jj = 0; jj < 4; jj++) {
                    int sl = (((quad & 1) * 2 + (jj >> 1)) << 4) + r16;
                    int t0 = __shfl((int)pk[kc * 2 + 0][jj & 1], sl);
                    int t1 = __shfl((int)pk[kc * 2 + 1][jj & 1], sl);
                    ((int*)&bq)[jj] = (quad >= 2) ? t1 : t0;
                }
                bf16x8 bqv = __builtin_bit_cast(bf16x8, bq);
                #pragma unroll
                for (int dt = 0; dt < 4; dt++)
                    o[mt][dt] = __builtin_amdgcn_mfma_f32_16x16x32_bf16(
                        vf[dt][kc], bqv, o[mt][dt], 0, 0, 0);
            }
        }
    }

    // ---- split-K combine via LDS adds ----
    if (w == 0) {
        #pragma unroll
        for (int mt = 0; mt < 2; mt++) {
            #pragma unroll
            for (int dt = 0; dt < 4; dt++)
                #pragma unroll
                for (int r = 0; r < 4; r++)
                    sO[mt][dt][r][lane] = o[mt][dt][r];
            sL[mt][lane] = lacc[mt];
        }
    }
    __syncthreads();
    if (w != 0) {
        #pragma unroll
        for (int mt = 0; mt < 2; mt++) {
            #pragma unroll
            for (int dt = 0; dt < 4; dt++)
                #pragma unroll
                for (int r = 0; r < 4; r++)
                    atomicAdd(&sO[mt][dt][r][lane], o[mt][dt][r]);
            atomicAdd(&sL[mt][lane], lacc[mt]);
        }
    }
    __syncthreads();
    if (w == 0) {
        const int b = bh >> 4, h = bh & 15;
        #pragma unroll
        for (int mt = 0; mt < 2; mt++) {
            float den = sL[mt][lane];
            den += __shfl_xor(den, 16);
            den += __shfl_xor(den, 32);
            float rden = 1.f / fmaxf(den, 1e-30f);
            int t = q0 + mt * 16 + r16;
            #pragma unroll
            for (int dt = 0; dt < 4; dt++) {
                float v0 = sO[mt][dt][0][lane] * rden;
                float v1 = sO[mt][dt][1][lane] * rden;
                float v2 = sO[mt][dt][2][lane] * rden;
                float v3 = sO[mt][dt][3][lane] * rden;
                int c = h * Dn + dt * 16 + quad * 4;
                size_t idx = ((size_t)(b * Tn + t)) * Cn + c;
                if (isbf) {
                    ushort4 pk4 = {f2bf(v0), f2bf(v1), f2bf(v2), f2bf(v3)};
                    *(ushort4*)((u16*)Y + idx) = pk4;
                } else {
                    float4 f4 = {v0, v1, v2, v3};
                    *(float4*)((float*)Y + idx) = f4;
                }
            }
        }
    }
}

extern "C" void kernel_launch(void* const* d_in, const int* in_sizes, int n_in,
                              void* d_out, int out_size, void* d_ws, size_t ws_size,
                              hipStream_t stream) {
    const void* X = d_in[0];   // x  [B,T,C]
    const void* W = d_in[1];   // W  [3C,C]
    void* Y = d_out;           // y  [B,T,C]

    const size_t per = (size_t)Bn * Hn * Tn * Dn;   // 4,194,304 elems
    int* flag = (int*)d_ws;
    u16* Q  = (u16*)((char*)d_ws + 256);
    u16* Kc = Q + per;
    u16* Vt = Kc + per;
    u16* Xb = Vt + per;                              // [Mdim x Kdim] bf16
    u16* Wb = Xb + (size_t)Mdim * Kdim;              // [Ndim x Kdim] bf16

    {
        const size_t nch = NXC + NWC;
        convert_in<<<dim3((unsigned)((nch + 255) / 256)), 256, 0, stream>>>(X, W, Xb, Wb, flag);
    }
    qkv_gemm<<<dim3(Ndim / 128, Mdim / 128), 256, 0, stream>>>(Xb, Wb, Q, Kc, Vt);
    attn<<<dim3(Bn * Hn, Tn / 32), 512, 0, stream>>>(Q, Kc, Vt, Y, flag);
}

// Round 9
// 190.519 us; speedup vs baseline: 1.8626x; 1.8626x over previous
//
#include <hip/hip_runtime.h>
#include <hip/hip_bf16.h>

// B=2, T=2048, C=1024, H=16, D=64
#define Bn 2
#define Tn 2048
#define Cn 1024
#define Hn 16
#define Dn 64
#define Mdim 4096   // B*T
#define Ndim 3072   // 3*C
#define Kdim 1024   // C

typedef unsigned short u16;
typedef __attribute__((ext_vector_type(8))) short bf16x8;   // 8 bf16 (4 VGPRs)
typedef __attribute__((ext_vector_type(4))) float f32x4;

__device__ __forceinline__ u16 f2bf(float v) {
    unsigned int x = __builtin_bit_cast(unsigned int, v);
    unsigned int r = (x + 0x7fffu + ((x >> 16) & 1u)) >> 16;  // RNE
    return (u16)r;
}

__device__ __forceinline__ unsigned int pack2(float a, float b) {
    return (unsigned int)f2bf(a) | ((unsigned int)f2bf(b) << 16);
}

// async global->LDS, 16B per lane. LDS dest = uniform base + lane*16 (m97).
__device__ __forceinline__ void async16(const void* g, void* l) {
    __builtin_amdgcn_global_load_lds(
        (const __attribute__((address_space(1))) void*)g,
        (__attribute__((address_space(3))) void*)(unsigned int)(unsigned long long)l,
        16, 0, 0);
}

// Inline dtype probe over X[0..511]: bf16 stream -> ~512 hits, fp32 -> ~66.
__device__ __forceinline__ int probe_inline(const unsigned int* __restrict__ X, int tid) {
    const int lane = tid & 63;
    int cnt = 0;
    #pragma unroll
    for (int i = 0; i < 8; i++) {
        unsigned int e = (X[lane * 8 + i] >> 7) & 0xFFu;
        cnt += (e >= 100u && e < 134u) ? 1 : 0;
    }
    #pragma unroll
    for (int off = 1; off < 64; off <<= 1) cnt += __shfl_xor(cnt, off);
    return cnt > 256 ? 1 : 0;
}

// ---------------------------------------------------------------------------
// Convert: X,W -> contiguous bf16 in ws (fp32: RNE; bf16: copy). Inline probe;
// block 0 persists the flag for attn.
// ---------------------------------------------------------------------------
#define NXC ((size_t)Mdim * Kdim / 8)   // 524288 chunks of 8 elems
#define NWC ((size_t)Ndim * Kdim / 8)   // 393216

__global__ __launch_bounds__(256) void convert_in(
        const void* __restrict__ Xv, const void* __restrict__ Wv,
        u16* __restrict__ Xb, u16* __restrict__ Wb, int* __restrict__ flag) {
    const int isbf = probe_inline((const unsigned int*)Xv, threadIdx.x);
    if (blockIdx.x == 0 && threadIdx.x == 0) *flag = isbf;
    size_t i = (size_t)blockIdx.x * 256 + threadIdx.x;
    if (i >= NXC + NWC) return;
    const void* src; u16* dst; size_t off;
    if (i < NXC) { src = Xv; dst = Xb; off = i; }
    else         { src = Wv; dst = Wb; off = i - NXC; }
    if (isbf) {
        ((uint4*)dst)[off] = ((const uint4*)src)[off];
    } else {
        const float4* s = (const float4*)src + off * 2;
        float4 a = s[0], b = s[1];
        ((uint4*)dst)[off] = (uint4){pack2(a.x, a.y), pack2(a.z, a.w),
                                     pack2(b.x, b.y), pack2(b.z, b.w)};
    }
}

// ---------------------------------------------------------------------------
// Kernel 1: QKV GEMM (m97: global_load_lds w16, unpadded LDS).
// qkv[m][f] = sum_c Xb[m][c]*Wb[f][c]. Q (x1/8) and K stored direct.
// V-section blocks (n0>=2048, block-uniform) SWAP the MFMA operands so the
// accumulator holds the transposed tile: C-layout col=r16 becomes t, making
// Vt[d][t] stores 32B-contiguous along t — same coalescing as Q/K, no LDS.
// ---------------------------------------------------------------------------
__global__ __launch_bounds__(256) void qkv_gemm(
        const u16* __restrict__ Xb, const u16* __restrict__ Wb,
        u16* __restrict__ Q, u16* __restrict__ Kc, u16* __restrict__ Vt) {
    __shared__ __align__(16) u16 sA[128 * 32];
    __shared__ __align__(16) u16 sB[128 * 32];

    const int tid  = threadIdx.x;
    const int lane = tid & 63;
    const int wv   = tid >> 6;
    const int quad = lane >> 4;
    const int r16  = lane & 15;
    const int m0 = blockIdx.y * 128;
    const int n0 = blockIdx.x * 128;
    const int wm = (wv >> 1) * 64;
    const int wn = (wv & 1) * 64;
    const int l4 = lane >> 2;
    const int c8 = (lane & 3) * 8;
    const bool vsec = (n0 >= 2048);   // block-uniform V section

    f32x4 acc[4][4];
    #pragma unroll
    for (int i = 0; i < 4; i++)
        #pragma unroll
        for (int j = 0; j < 4; j++)
            acc[i][j] = (f32x4){0.f, 0.f, 0.f, 0.f};

    for (int k0 = 0; k0 < Kdim; k0 += 32) {
        __syncthreads();
        #pragma unroll
        for (int i = 0; i < 2; i++) {
            const int rg = (wv + 4 * i) * 16;
            async16(Xb + (size_t)(m0 + rg + l4) * Kdim + k0 + c8, sA + rg * 32);
            async16(Wb + (size_t)(n0 + rg + l4) * Kdim + k0 + c8, sB + rg * 32);
        }
        __syncthreads();

        bf16x8 af[4], bfr[4];
        #pragma unroll
        for (int mt = 0; mt < 4; mt++)
            af[mt] = *(const bf16x8*)(sA + (wm + mt * 16 + r16) * 32 + quad * 8);
        #pragma unroll
        for (int nt = 0; nt < 4; nt++)
            bfr[nt] = *(const bf16x8*)(sB + (wn + nt * 16 + r16) * 32 + quad * 8);
        if (vsec) {
            // transposed accumulate: acc[nt][mt] = W_tile · X_tile^T
            #pragma unroll
            for (int mt = 0; mt < 4; mt++)
                #pragma unroll
                for (int nt = 0; nt < 4; nt++)
                    acc[nt][mt] = __builtin_amdgcn_mfma_f32_16x16x32_bf16(
                        bfr[nt], af[mt], acc[nt][mt], 0, 0, 0);
        } else {
            #pragma unroll
            for (int mt = 0; mt < 4; mt++)
                #pragma unroll
                for (int nt = 0; nt < 4; nt++)
                    acc[mt][nt] = __builtin_amdgcn_mfma_f32_16x16x32_bf16(
                        af[mt], bfr[nt], acc[mt][nt], 0, 0, 0);
        }
    }

    if (!vsec) {
        // C/D layout: col=r16 (=n=f), row=quad*4+r (=m) [m89/m91]
        #pragma unroll
        for (int mt = 0; mt < 4; mt++) {
            #pragma unroll
            for (int nt = 0; nt < 4; nt++) {
                #pragma unroll
                for (int r = 0; r < 4; r++) {
                    int m = m0 + wm + mt * 16 + quad * 4 + r;
                    int f = n0 + wn + nt * 16 + r16;
                    float v = acc[mt][nt][r];
                    int b = m >> 11, t = m & 2047;
                    int sect = f >> 10;
                    int h = (f >> 6) & 15;
                    int d = f & 63;
                    int bh = b * Hn + h;
                    if (sect == 0) {
                        Q[((size_t)(bh * Tn + t)) * Dn + d] = f2bf(v * 0.125f);
                    } else {
                        Kc[((size_t)(bh * Tn + t)) * Dn + d] = f2bf(v);
                    }
                }
            }
        }
    } else {
        // transposed C: col=r16 = m(t), row=quad*4+r = f(d)
        const int h  = ((n0 + wn) >> 6) & 15;
        const int bb = (m0 + wm) >> 11;
        const int t0w = (m0 + wm) & 2047;
        const int bh = bb * Hn + h;
        #pragma unroll
        for (int nt = 0; nt < 4; nt++) {
            #pragma unroll
            for (int mt = 0; mt < 4; mt++) {
                #pragma unroll
                for (int r = 0; r < 4; r++) {
                    int t = t0w + mt * 16 + r16;
                    int d = (wn & 63) + nt * 16 + quad * 4 + r;   // wn&63==0
                    Vt[((size_t)(bh * Dn + d)) * Tn + t] = f2bf(acc[nt][mt][r]);
                }
            }
        }
    }
}

// ---------------------------------------------------------------------------
// Kernel 2: causal flash attention (R6 verbatim — best measured, 76 µs).
// Transposed S^T = K·Q^T; P^T -> PV B-operand via in-register lane shuffles;
// fixed-shift softmax (p=exp(s-8), additive partials); split-K 4 waves,
// hierarchical LDS combine at the end only.
// ---------------------------------------------------------------------------
__global__ __launch_bounds__(256) void attn(
        const u16* __restrict__ Q, const u16* __restrict__ Kc,
        const u16* __restrict__ Vt, void* __restrict__ Y,
        const int* __restrict__ flag) {
    __shared__ float sO2[2][2][4][4][64];   // 16384 B
    __shared__ float sL2[2][2][64];         // 1024 B

    const int isbf = *flag;
    const int tid  = threadIdx.x;
    const int lane = tid & 63;
    const int w    = tid >> 6;      // split-K index 0..3
    const int quad = lane >> 4;
    const int r16  = lane & 15;
    const int bh = blockIdx.x;                   // 0..31
    const int qt = gridDim.y - 1 - blockIdx.y;   // deep tiles first
    const int q0 = qt * 32;
    const size_t qkBase = (size_t)bh * Tn * Dn;
    const size_t vBase  = (size_t)bh * Dn * Tn;

    // Q frags (B-operand of S^T): B[k=quad*8+j][n=r16]
    bf16x8 aq[2][2];
    #pragma unroll
    for (int mt = 0; mt < 2; mt++) {
        const u16* qp = Q + qkBase + (size_t)(q0 + mt * 16 + r16) * Dn;
        aq[mt][0] = *(const bf16x8*)(qp + quad * 8);
        aq[mt][1] = *(const bf16x8*)(qp + 32 + quad * 8);
    }

    float lacc[2] = {0.f, 0.f};
    f32x4 o[2][4];   // O^T tiles [mt][dt], C-layout: row=d_local=quad*4+r, col=q=r16
    #pragma unroll
    for (int mt = 0; mt < 2; mt++)
        #pragma unroll
        for (int dt = 0; dt < 4; dt++) o[mt][dt] = (f32x4){0.f, 0.f, 0.f, 0.f};

    const int nkb = (q0 >> 6) + 1;
    for (int kb = w; kb < nkb; kb += 4) {
        const int kbase = kb * 64;
        const int diag = (kb == nkb - 1);

        // K frags (A-operand of S^T): A[m=key16=r16][k=quad*8+j]
        bf16x8 kf[4][2];
        #pragma unroll
        for (int nt = 0; nt < 4; nt++) {
            const u16* kp = Kc + qkBase + (size_t)(kbase + nt * 16 + r16) * Dn;
            kf[nt][0] = *(const bf16x8*)(kp + quad * 8);
            kf[nt][1] = *(const bf16x8*)(kp + 32 + quad * 8);
        }
        // V frags (A-operand of PV): A[m=d16=r16][k=quad*8+j]
        bf16x8 vf[4][2];
        #pragma unroll
        for (int dt = 0; dt < 4; dt++) {
            const u16* vp = Vt + vBase + (size_t)(dt * 16 + r16) * Tn + kbase;
            vf[dt][0] = *(const bf16x8*)(vp + quad * 8);
            vf[dt][1] = *(const bf16x8*)(vp + 32 + quad * 8);
        }

        #pragma unroll
        for (int mt = 0; mt < 2; mt++) {
            // S^T tile nt: value(lane(quad,r16), reg r) = S^T[nt*16+quad*4+r][r16]
            f32x4 s[4];
            #pragma unroll
            for (int nt = 0; nt < 4; nt++) {
                f32x4 z = (f32x4){0.f, 0.f, 0.f, 0.f};
                z = __builtin_amdgcn_mfma_f32_16x16x32_bf16(kf[nt][0], aq[mt][0], z, 0, 0, 0);
                z = __builtin_amdgcn_mfma_f32_16x16x32_bf16(kf[nt][1], aq[mt][1], z, 0, 0, 0);
                s[nt] = z;
            }
            if (diag) {
                const int query = q0 + mt * 16 + r16;
                #pragma unroll
                for (int nt = 0; nt < 4; nt++)
                    #pragma unroll
                    for (int r = 0; r < 4; r++) {
                        int key = kbase + nt * 16 + quad * 4 + r;
                        if (key > query) s[nt][r] = -1e30f;
                    }
            }
            // p = exp(s - 8); accumulate l; pack pairs for shuffling
            unsigned int pk[4][2];
            #pragma unroll
            for (int nt = 0; nt < 4; nt++) {
                float p0 = __expf(s[nt][0] - 8.f);
                float p1 = __expf(s[nt][1] - 8.f);
                float p2 = __expf(s[nt][2] - 8.f);
                float p3 = __expf(s[nt][3] - 8.f);
                lacc[mt] += (p0 + p1) + (p2 + p3);
                pk[nt][0] = pack2(p0, p1);
                pk[nt][1] = pack2(p2, p3);
            }
            // build PV B-frags in-register: B[k=quad*8+j][n=r16]
            #pragma unroll
            for (int kc = 0; kc < 2; kc++) {
                int4 bq;
                #pragma unroll
                for (int jj = 0; jj < 4; jj++) {
                    int sl = (((quad & 1) * 2 + (jj >> 1)) << 4) + r16;
                    int t0 = __shfl((int)pk[kc * 2 + 0][jj & 1], sl);
                    int t1 = __shfl((int)pk[kc * 2 + 1][jj & 1], sl);
                    ((int*)&bq)[jj] = (quad >= 2) ? t1 : t0;
                }
                bf16x8 bqv = __builtin_bit_cast(bf16x8, bq);
                #pragma unroll
                for (int dt = 0; dt < 4; dt++)
                    o[mt][dt] = __builtin_amdgcn_mfma_f32_16x16x32_bf16(
                        vf[dt][kc], bqv, o[mt][dt], 0, 0, 0);
            }
        }
    }

    // ---- hierarchical split-K combine ----
    if (w >= 2) {
        #pragma unroll
        for (int mt = 0; mt < 2; mt++) {
            #pragma unroll
            for (int dt = 0; dt < 4; dt++)
                #pragma unroll
                for (int r = 0; r < 4; r++)
                    sO2[w - 2][mt][dt][r][lane] = o[mt][dt][r];
            sL2[w - 2][mt][lane] = lacc[mt];
        }
    }
    __syncthreads();
    if (w < 2) {
        #pragma unroll
        for (int mt = 0; mt < 2; mt++) {
            #pragma unroll
            for (int dt = 0; dt < 4; dt++)
                #pragma unroll
                for (int r = 0; r < 4; r++)
                    o[mt][dt][r] += sO2[w][mt][dt][r][lane];
            lacc[mt] += sL2[w][mt][lane];
        }
    }
    __syncthreads();
    if (w == 1) {
        #pragma unroll
        for (int mt = 0; mt < 2; mt++) {
            #pragma unroll
            for (int dt = 0; dt < 4; dt++)
                #pragma unroll
                for (int r = 0; r < 4; r++)
                    sO2[0][mt][dt][r][lane] = o[mt][dt][r];
            sL2[0][mt][lane] = lacc[mt];
        }
    }
    __syncthreads();
    if (w == 0) {
        const int b = bh >> 4, h = bh & 15;
        #pragma unroll
        for (int mt = 0; mt < 2; mt++) {
            float den = lacc[mt] + sL2[0][mt][lane];
            den += __shfl_xor(den, 16);
            den += __shfl_xor(den, 32);
            float rden = 1.f / fmaxf(den, 1e-30f);
            int t = q0 + mt * 16 + r16;
            #pragma unroll
            for (int dt = 0; dt < 4; dt++) {
                float v0 = (o[mt][dt][0] + sO2[0][mt][dt][0][lane]) * rden;
                float v1 = (o[mt][dt][1] + sO2[0][mt][dt][1][lane]) * rden;
                float v2 = (o[mt][dt][2] + sO2[0][mt][dt][2][lane]) * rden;
                float v3 = (o[mt][dt][3] + sO2[0][mt][dt][3][lane]) * rden;
                int c = h * Dn + dt * 16 + quad * 4;
                size_t idx = ((size_t)(b * Tn + t)) * Cn + c;
                if (isbf) {
                    ushort4 pk4 = {f2bf(v0), f2bf(v1), f2bf(v2), f2bf(v3)};
                    *(ushort4*)((u16*)Y + idx) = pk4;
                } else {
                    float4 f4 = {v0, v1, v2, v3};
                    *(float4*)((float*)Y + idx) = f4;
                }
            }
        }
    }
}

extern "C" void kernel_launch(void* const* d_in, const int* in_sizes, int n_in,
                              void* d_out, int out_size, void* d_ws, size_t ws_size,
                              hipStream_t stream) {
    const void* X = d_in[0];   // x  [B,T,C]
    const void* W = d_in[1];   // W  [3C,C]
    void* Y = d_out;           // y  [B,T,C]

    const size_t per = (size_t)Bn * Hn * Tn * Dn;   // 4,194,304 elems
    int* flag = (int*)d_ws;
    u16* Q  = (u16*)((char*)d_ws + 256);
    u16* Kc = Q + per;
    u16* Vt = Kc + per;
    u16* Xb = Vt + per;                              // [Mdim x Kdim] bf16
    u16* Wb = Xb + (size_t)Mdim * Kdim;              // [Ndim x Kdim] bf16

    {
        const size_t nch = NXC + NWC;
        convert_in<<<dim3((unsigned)((nch + 255) / 256)), 256, 0, stream>>>(X, W, Xb, Wb, flag);
    }
    qkv_gemm<<<dim3(Ndim / 128, Mdim / 128), 256, 0, stream>>>(Xb, Wb, Q, Kc, Vt);
    attn<<<dim3(Bn * Hn, Tn / 32), 256, 0, stream>>>(Q, Kc, Vt, Y, flag);
}